// Round 12
// baseline (313.258 us; speedup 1.0000x reference)
//
#include <hip/hip_runtime.h>
#include <hip/hip_bf16.h>
#include <hip/hip_fp16.h>

// ---------------------------------------------------------------------------
// GCN link predictor, fp16 intermediates + MFMA GEMMs (fp32 accumulate):
//   g1 = (X @ W1) * dinv[row]                    (MFMA GEMM, stored fp16)
//   z1 = relu(dinv*(g1[v] + sum g1[s]) + b1)     (gather; z1 stays in LDS)
//   g2 = (z1 @ W2) * dinv[row]                   (MFMA fused in gather1 epi)
//   z2 = relu(dinv*(g2[v] + sum g2[s]) + b2)     (gather)
//   out[e] = dot(z2[s], z2[d])
// CSR via slab bucket sort (bucket = dst>>8, CAP=5120 >> 15 sigma).
// R11 lesson: 16 slots / 16 groups made dynamic scheduling vacuous (1 node
// per group = static). R12: 64 nodes/block -> ~4 nodes/group pulled from the
// LDS cursor (real balancing, variance of group work ~halved), barrier +
// B-frag loads + MFMA epilogue amortized over 4 M-tiles. Unfusing is NOT
// profitable: it costs a 50MB z1 round-trip + a launch (R11 accounting).
// ---------------------------------------------------------------------------

typedef _Float16 half8 __attribute__((ext_vector_type(8)));
typedef float floatx4 __attribute__((ext_vector_type(4)));

#define BK_SHIFT 8
#define BSC_EDGES 2048  // edges per block in binning scatter
#define SLAB_CAP 5120   // per-bucket slab capacity (mean 4092, sd 64)
#define WPAD 136        // padded LDS row stride (halfs)
#define GG_NODES 64     // nodes per fused gather+gemm block

// ---- transpose + fp16-cast weights; blocks 0..3 also zero bfill
__global__ __launch_bounds__(128) void k_wprep(const float* __restrict__ W1,
                                               const float* __restrict__ W2,
                                               _Float16* __restrict__ WT1,
                                               _Float16* __restrict__ WT2,
                                               int* __restrict__ bfill) {
    int b = blockIdx.x;               // 0..255
    const float* W = (b < 128) ? W1 : W2;
    _Float16* WT = (b < 128) ? WT1 : WT2;
    int k = b & 127;
    int c = threadIdx.x;
    WT[c * 128 + k] = (_Float16)W[k * 128 + c];
    if (b < 4) bfill[b * 128 + c] = 0;   // 512 ints >= NBK
}

// ---- LDS-binned scatter of (src,dst) pairs into per-bucket slabs.
__global__ __launch_bounds__(256) void k_bscatter(const int* __restrict__ src,
                                                  const int* __restrict__ dst,
                                                  int* __restrict__ bfill,
                                                  int2* __restrict__ pairs,
                                                  int E, int nbk) {
    __shared__ int lcnt[1024];    // counts, then fill cursor (= lbase)
    __shared__ int delta[1024];   // slab_dest - lbase per bucket
    __shared__ int ssum[256];     // block-scan workspace
    __shared__ int2 stage[BSC_EDGES];
    int tid = threadIdx.x;
    int e0 = blockIdx.x * BSC_EDGES;
    int nloc = E - e0; if (nloc > BSC_EDGES) nloc = BSC_EDGES;

    for (int b = tid; b < nbk; b += 256) lcnt[b] = 0;
    __syncthreads();

    int d[BSC_EDGES / 256], s[BSC_EDGES / 256];
#pragma unroll
    for (int k = 0; k < BSC_EDGES / 256; ++k) {
        int e = e0 + k * 256 + tid;
        if (e < E) {
            d[k] = dst[e];
            s[k] = src[e];
            atomicAdd(&lcnt[d[k] >> BK_SHIFT], 1);
        } else d[k] = -1;
    }
    __syncthreads();

    const int gpb = (nbk + 255) >> 8;   // <=4 for nbk<=1024
    int c[4], mysum = 0;
    for (int t = 0; t < gpb; ++t) {
        int b = tid * gpb + t;
        c[t] = (b < nbk) ? lcnt[b] : 0;
        mysum += c[t];
    }
    ssum[tid] = mysum;
    __syncthreads();
    for (int off = 1; off < 256; off <<= 1) {
        int t = (tid >= off) ? ssum[tid - off] : 0;
        __syncthreads();
        ssum[tid] += t;
        __syncthreads();
    }
    int base = ssum[tid] - mysum;
    for (int t = 0; t < gpb; ++t) {
        int b = tid * gpb + t;
        if (b < nbk) {
            int g = c[t] ? atomicAdd(&bfill[b], c[t]) : 0;
            delta[b] = b * SLAB_CAP + g - base;   // slab dest - lbase
            lcnt[b] = base;                        // cursor starts at lbase
            base += c[t];
        }
    }
    __syncthreads();

#pragma unroll
    for (int k = 0; k < BSC_EDGES / 256; ++k) {
        if (d[k] >= 0) {
            int b = d[k] >> BK_SHIFT;
            int lp = atomicAdd(&lcnt[b], 1);
            int2 p; p.x = s[k]; p.y = d[k];
            stage[lp] = p;
        }
    }
    __syncthreads();

    for (int j = tid; j < nloc; j += 256) {
        int2 p = stage[j];
        pairs[delta[p.y >> BK_SHIFT] + j] = p;
    }
}

// ---- fused CSR build, one block per bucket slab (256 nodes)
__global__ __launch_bounds__(256) void k_csr(const int2* __restrict__ pairs,
                                             const int* __restrict__ bfill,
                                             int* __restrict__ row_start,
                                             int* __restrict__ cnt,
                                             float* __restrict__ dinv,
                                             int* __restrict__ srcs, int n) {
    __shared__ int lcnt[256];
    __shared__ int lpos[256];
    int tid = threadIdx.x;
    int b = blockIdx.x;
    lcnt[tid] = 0;
    __syncthreads();
    int beg = b * SLAB_CAP, end = beg + bfill[b];
    for (int i = beg + tid; i < end; i += 256)
        atomicAdd(&lcnt[pairs[i].y & 255], 1);
    __syncthreads();
    int c = lcnt[tid];
    lpos[tid] = c;
    __syncthreads();
    for (int off = 1; off < 256; off <<= 1) {
        int t = (tid >= off) ? lpos[tid - off] : 0;
        __syncthreads();
        lpos[tid] += t;
        __syncthreads();
    }
    int rs = beg + lpos[tid] - c;   // row start (slab-relative, gaps ok)
    int v = (b << BK_SHIFT) + tid;
    if (v < n) {
        row_start[v] = rs;
        cnt[v] = c;
        dinv[v] = rsqrtf((float)c + 1.0f);
    }
    __syncthreads();
    lpos[tid] = rs;                 // reuse as fill cursor
    __syncthreads();
    for (int i = beg + tid; i < end; i += 256) {
        int2 p = pairs[i];
        int loc = atomicAdd(&lpos[p.y & 255], 1);
        srcs[loc] = p.x;
    }
}

// ---------------------------------------------------------------------------
// MFMA GEMM (layer 1): G[r][c] = dinv[r] * sum_k X[r][k]*W[k][c]
// Block 256 thr = 4 waves, M=32/wave -> 128 rows/block. WT staged in LDS.
// ---------------------------------------------------------------------------
__global__ __launch_bounds__(256) void k_gemm_mfma(const float* __restrict__ X,
                                                   const _Float16* __restrict__ WT,
                                                   const float* __restrict__ dinv,
                                                   _Float16* __restrict__ G, int n) {
    __shared__ _Float16 Wl[128 * WPAD];
    int tid = threadIdx.x;
    {
        const half8* w8 = (const half8*)WT;
#pragma unroll
        for (int i = 0; i < 8; ++i) {
            int idx = i * 256 + tid;
            int r = idx >> 4, cc = idx & 15;
            *(half8*)(Wl + r * WPAD + cc * 8) = w8[idx];
        }
    }
    __syncthreads();

    int wave = tid >> 6, lane = tid & 63;
    int q = lane >> 4, ln = lane & 15;
    int m0 = blockIdx.x * 128 + wave * 32;
    int mA0 = m0 + ln;      if (mA0 >= n) mA0 = n - 1;
    int mA1 = m0 + 16 + ln; if (mA1 >= n) mA1 = n - 1;
    const float* xr0 = X + (size_t)mA0 * 128;
    const float* xr1 = X + (size_t)mA1 * 128;

    floatx4 acc[2][8];
#pragma unroll
    for (int p = 0; p < 2; ++p)
#pragma unroll
        for (int t = 0; t < 8; ++t) acc[p][t] = (floatx4){0.f, 0.f, 0.f, 0.f};

#pragma unroll
    for (int kc = 0; kc < 128; kc += 32) {
        half8 a0, a1;
        {
            const float4* p0 = (const float4*)(xr0 + kc + q * 8);
            float4 f0 = p0[0], f1 = p0[1];
            a0[0] = (_Float16)f0.x; a0[1] = (_Float16)f0.y;
            a0[2] = (_Float16)f0.z; a0[3] = (_Float16)f0.w;
            a0[4] = (_Float16)f1.x; a0[5] = (_Float16)f1.y;
            a0[6] = (_Float16)f1.z; a0[7] = (_Float16)f1.w;
            const float4* p1 = (const float4*)(xr1 + kc + q * 8);
            float4 g0 = p1[0], g1 = p1[1];
            a1[0] = (_Float16)g0.x; a1[1] = (_Float16)g0.y;
            a1[2] = (_Float16)g0.z; a1[3] = (_Float16)g0.w;
            a1[4] = (_Float16)g1.x; a1[5] = (_Float16)g1.y;
            a1[6] = (_Float16)g1.z; a1[7] = (_Float16)g1.w;
        }
#pragma unroll
        for (int t = 0; t < 8; ++t) {
            half8 b = *(const half8*)(Wl + (size_t)(t * 16 + ln) * WPAD + kc + q * 8);
            acc[0][t] = __builtin_amdgcn_mfma_f32_16x16x32_f16(a0, b, acc[0][t], 0, 0, 0);
            acc[1][t] = __builtin_amdgcn_mfma_f32_16x16x32_f16(a1, b, acc[1][t], 0, 0, 0);
        }
    }

#pragma unroll
    for (int p = 0; p < 2; ++p) {
#pragma unroll
        for (int r = 0; r < 4; ++r) {
            int row = m0 + p * 16 + q * 4 + r;
            if (row < n) {
                float dv = dinv[row];
                _Float16* grow = G + (size_t)row * 128 + ln;
#pragma unroll
                for (int t = 0; t < 8; ++t)
                    grow[t * 16] = (_Float16)(acc[p][t][r] * dv);
            }
        }
    }
}

// ---------------------------------------------------------------------------
// Fused layer-1 gather + layer-2 GEMM, 64 nodes/block:
// 16 groups x 16 lanes pull node slots (~4 each) from an LDS cursor -- real
// load balancing across Poisson degrees. W2 fragments in VGPRs (loaded once).
// After one barrier: 4 M-tiles of MFMA per wave (cols wave*32..+32).
// ---------------------------------------------------------------------------
__global__ __launch_bounds__(256, 4) void k_gather_gemm(const _Float16* __restrict__ G,
                                                        const int* __restrict__ srcs,
                                                        const int* __restrict__ row_start,
                                                        const int* __restrict__ cnt,
                                                        const float* __restrict__ dinv,
                                                        const float* __restrict__ bias,
                                                        const _Float16* __restrict__ WT2,
                                                        _Float16* __restrict__ G2, int n) {
    __shared__ _Float16 zl[GG_NODES * WPAD];   // z1 rows
    __shared__ int cursor;
    int tid = threadIdx.x;
    int wave = tid >> 6, wl = tid & 63;
    int q = wl >> 4, ln = wl & 15;

    // B fragments -> registers (wave w owns cols [w*32, w*32+32))
    half8 bfr[4][2];
#pragma unroll
    for (int kq = 0; kq < 4; ++kq)
#pragma unroll
        for (int t = 0; t < 2; ++t)
            bfr[kq][t] = *(const half8*)(WT2 +
                (size_t)(wave * 32 + t * 16 + ln) * 128 + kq * 32 + q * 8);

    if (tid == 0) cursor = 0;
    __syncthreads();

    int lane = tid & 15;                // lane within 16-lane node group
    const half8* G8 = (const half8*)G;
    const float4* b4 = (const float4*)bias;

    for (;;) {
        int slot = 0;
        if (lane == 0) slot = atomicAdd(&cursor, 1);
        slot = __shfl(slot, 0, 16);
        if (slot >= GG_NODES) break;
        int v = blockIdx.x * GG_NODES + slot;
        half8 zo;
        if (v < n) {
            half8 self = G8[(size_t)v * 16 + lane];
            float acc[8], acc2[8];
#pragma unroll
            for (int j = 0; j < 8; ++j) { acc[j] = (float)self[j]; acc2[j] = 0.f; }

            int beg = row_start[v], deg = cnt[v];
            int e = 0;
            for (; e + 3 < deg; e += 4) {
                int s0 = srcs[beg + e];
                int s1 = srcs[beg + e + 1];
                int s2 = srcs[beg + e + 2];
                int s3 = srcs[beg + e + 3];
                half8 t0 = G8[(size_t)s0 * 16 + lane];
                half8 t1 = G8[(size_t)s1 * 16 + lane];
                half8 t2 = G8[(size_t)s2 * 16 + lane];
                half8 t3 = G8[(size_t)s3 * 16 + lane];
#pragma unroll
                for (int j = 0; j < 8; ++j) {
                    acc[j]  += (float)t0[j] + (float)t1[j];
                    acc2[j] += (float)t2[j] + (float)t3[j];
                }
            }
            for (; e < deg; ++e) {
                int s0 = srcs[beg + e];
                half8 t0 = G8[(size_t)s0 * 16 + lane];
#pragma unroll
                for (int j = 0; j < 8; ++j) acc[j] += (float)t0[j];
            }

            float dv = dinv[v];
            float4 bb0 = b4[lane * 2], bb1 = b4[lane * 2 + 1];
            float bf[8] = {bb0.x, bb0.y, bb0.z, bb0.w, bb1.x, bb1.y, bb1.z, bb1.w};
#pragma unroll
            for (int j = 0; j < 8; ++j) {
                float z = dv * (acc[j] + acc2[j]) + bf[j];
                zo[j] = (_Float16)fmaxf(z, 0.f);
            }
        } else {
#pragma unroll
            for (int j = 0; j < 8; ++j) zo[j] = (_Float16)0.f;
        }
        *(half8*)(zl + slot * WPAD + lane * 8) = zo;
    }
    __syncthreads();

    // ---- MFMA: z1 (64x128, LDS) @ W2 (registers) -> G2 rows, 4 M-tiles
#pragma unroll
    for (int mt = 0; mt < 4; ++mt) {
        floatx4 acc[2];
        acc[0] = (floatx4){0.f, 0.f, 0.f, 0.f};
        acc[1] = (floatx4){0.f, 0.f, 0.f, 0.f};
#pragma unroll
        for (int kq = 0; kq < 4; ++kq) {
            half8 a = *(const half8*)(zl + (mt * 16 + ln) * WPAD + kq * 32 + q * 8);
            acc[0] = __builtin_amdgcn_mfma_f32_16x16x32_f16(a, bfr[kq][0], acc[0], 0, 0, 0);
            acc[1] = __builtin_amdgcn_mfma_f32_16x16x32_f16(a, bfr[kq][1], acc[1], 0, 0, 0);
        }
#pragma unroll
        for (int r = 0; r < 4; ++r) {
            int gv = blockIdx.x * GG_NODES + mt * 16 + q * 4 + r;
            if (gv < n) {
                float dv = dinv[gv];
#pragma unroll
                for (int t = 0; t < 2; ++t)
                    G2[(size_t)gv * 128 + wave * 32 + t * 16 + ln] =
                        (_Float16)(acc[t][r] * dv);
            }
        }
    }
}

// ---------------------------------------------------------------------------
// Layer-2 gather + bias + relu -> z2 (fp16). 16 lanes/node, half8.
// ---------------------------------------------------------------------------
__global__ __launch_bounds__(256) void k_gather_relu(const _Float16* __restrict__ G,
                                                     const int* __restrict__ srcs,
                                                     const int* __restrict__ row_start,
                                                     const int* __restrict__ cnt,
                                                     const float* __restrict__ dinv,
                                                     const float* __restrict__ bias,
                                                     _Float16* __restrict__ Z, int n) {
    int v = blockIdx.x * 16 + (threadIdx.x >> 4);
    int lane = threadIdx.x & 15;
    if (v >= n) return;
    const half8* G8 = (const half8*)G;

    half8 self = G8[(size_t)v * 16 + lane];
    float acc[8], acc2[8];
#pragma unroll
    for (int j = 0; j < 8; ++j) { acc[j] = (float)self[j]; acc2[j] = 0.f; }

    int beg = row_start[v], deg = cnt[v];
    int e = 0;
    for (; e + 3 < deg; e += 4) {
        int s0 = srcs[beg + e];
        int s1 = srcs[beg + e + 1];
        int s2 = srcs[beg + e + 2];
        int s3 = srcs[beg + e + 3];
        half8 t0 = G8[(size_t)s0 * 16 + lane];
        half8 t1 = G8[(size_t)s1 * 16 + lane];
        half8 t2 = G8[(size_t)s2 * 16 + lane];
        half8 t3 = G8[(size_t)s3 * 16 + lane];
#pragma unroll
        for (int j = 0; j < 8; ++j) {
            acc[j]  += (float)t0[j] + (float)t1[j];
            acc2[j] += (float)t2[j] + (float)t3[j];
        }
    }
    for (; e < deg; ++e) {
        int s0 = srcs[beg + e];
        half8 t0 = G8[(size_t)s0 * 16 + lane];
#pragma unroll
        for (int j = 0; j < 8; ++j) acc[j] += (float)t0[j];
    }

    float dv = dinv[v];
    const float4* b4 = (const float4*)bias;
    float4 bb0 = b4[lane * 2], bb1 = b4[lane * 2 + 1];
    float bf[8] = {bb0.x, bb0.y, bb0.z, bb0.w, bb1.x, bb1.y, bb1.z, bb1.w};
    half8 zo;
#pragma unroll
    for (int j = 0; j < 8; ++j) {
        float z = dv * (acc[j] + acc2[j]) + bf[j];
        zo[j] = (_Float16)fmaxf(z, 0.f);
    }
    ((half8*)Z)[(size_t)v * 16 + lane] = zo;
}

// ---------------------------------------------------------------------------
// Decode: out[e] = dot(Z[s_e], Z[d_e]) over 128 dims (fp16 rows, fp32 accum).
// ---------------------------------------------------------------------------
__global__ __launch_bounds__(256) void k_decode(const _Float16* __restrict__ Z,
                                                const int* __restrict__ eli,
                                                float* __restrict__ out, int el) {
    int sub = threadIdx.x >> 4, lane = threadIdx.x & 15;
    int e = blockIdx.x * 16 + sub;
    if (e >= el) return;
    int s = eli[e], d = eli[el + e];
    const half8* Z8 = (const half8*)Z;
    half8 a = Z8[(size_t)s * 16 + lane];
    half8 b = Z8[(size_t)d * 16 + lane];
    float dot = 0.f;
#pragma unroll
    for (int j = 0; j < 8; ++j) dot += (float)a[j] * (float)b[j];
#pragma unroll
    for (int off = 8; off; off >>= 1) dot += __shfl_down(dot, off, 16);
    if (lane == 0) out[e] = dot;
}

extern "C" void kernel_launch(void* const* d_in, const int* in_sizes, int n_in,
                              void* d_out, int out_size, void* d_ws, size_t ws_size,
                              hipStream_t stream) {
    const float* x  = (const float*)d_in[0];
    const int*  ei  = (const int*)d_in[1];
    const int*  eli = (const int*)d_in[2];
    const float* W1 = (const float*)d_in[3];
    const float* b1 = (const float*)d_in[4];
    const float* W2 = (const float*)d_in[5];
    const float* b2 = (const float*)d_in[6];
    float* out = (float*)d_out;

    const int N  = in_sizes[0] / 128;
    const int E  = in_sizes[1] / 2;
    const int EL = in_sizes[2] / 2;
    const int* src = ei;
    const int* dst = ei + E;
    const int NBK = (N + 255) >> BK_SHIFT;   // 391 for N=100000

    char* ws = (char*)d_ws;
    size_t off = 0;
    auto alloc = [&](size_t bytes) -> void* {
        void* p = ws + off;
        off += bytes;
        off = (off + 255) & ~(size_t)255;
        return p;
    };
    int*       cnt       = (int*)alloc((size_t)N * 4);
    int*       row_start = (int*)alloc((size_t)N * 4);
    float*     dinv      = (float*)alloc((size_t)N * 4);
    int*       bfill     = (int*)alloc(4096);
    _Float16*  WT1       = (_Float16*)alloc(128 * 128 * 2);
    _Float16*  WT2       = (_Float16*)alloc(128 * 128 * 2);
    int*       srcs      = (int*)alloc((size_t)NBK * SLAB_CAP * 4);
    int2*      pairs     = (int2*)alloc((size_t)NBK * SLAB_CAP * 8);
    _Float16*  buf0      = (_Float16*)alloc((size_t)N * 128 * 2);  // G1, then z2
    _Float16*  buf1      = (_Float16*)alloc((size_t)N * 128 * 2);  // G2

    // weight prep + bfill zero (one launch)
    k_wprep<<<256, 128, 0, stream>>>(W1, W2, WT1, WT2, bfill);

    // CSR build: slab bucket sort (no count/scan pre-pass)
    k_bscatter<<<(E + BSC_EDGES - 1) / BSC_EDGES, 256, 0, stream>>>(src, dst, bfill, pairs, E, NBK);
    k_csr<<<NBK, 256, 0, stream>>>(pairs, bfill, row_start, cnt, dinv, srcs, N);

    // layer 1 GEMM: g1 = (x@W1)*dinv -> buf0 (fp16)
    k_gemm_mfma<<<(N + 127) / 128, 256, 0, stream>>>(x, WT1, dinv, buf0, N);
    // fused: z1 = relu(agg(g1)+b1) (LDS only) ; G2 = (z1@W2)*dinv -> buf1
    k_gather_gemm<<<(N + GG_NODES - 1) / GG_NODES, 256, 0, stream>>>(buf0, srcs, row_start, cnt, dinv, b1, WT2, buf1, N);
    // layer 2 gather: z2 = relu(agg(G2)+b2) -> buf0
    k_gather_relu<<<(N + 15) / 16, 256, 0, stream>>>(buf1, srcs, row_start, cnt, dinv, b2, buf0, N);
    // decode
    k_decode<<<(EL + 15) / 16, 256, 0, stream>>>(buf0, eli, out, EL);
}

// Round 13
// 307.868 us; speedup vs baseline: 1.0175x; 1.0175x over previous
//
#include <hip/hip_runtime.h>
#include <hip/hip_bf16.h>
#include <hip/hip_fp16.h>

// ---------------------------------------------------------------------------
// GCN link predictor, fp16 intermediates + MFMA GEMMs (fp32 accumulate):
//   g1 = (X @ W1) * dinv[row]                    (MFMA GEMM, fp32 A)
//   z1 = relu(dinv*(g1[v] + sum g1[s]) + b1)     (gather, 61 µs proven shape)
//   g2 = (z1 @ W2) * dinv[row]                   (MFMA GEMM, fp16 A)
//   z2 = relu(dinv*(g2[v] + sum g2[s]) + b2)     (gather)
//   out[e] = dot(z2[s], z2[d])
// CSR via slab bucket sort (bucket = dst>>8, CAP=5120 >> 15 sigma).
// R10-R12 lesson: fusing gather+gemm2 pins the gather at ~80 µs vs 61
// standalone (cause resisted 3 theories: L1 thrash, occupancy, imbalance);
// unfused pair = 61 + ~13 beats fused 80-85. UNFUSED is the right structure.
// ---------------------------------------------------------------------------

typedef _Float16 half8 __attribute__((ext_vector_type(8)));
typedef float floatx4 __attribute__((ext_vector_type(4)));

#define BK_SHIFT 8
#define BSC_EDGES 2048  // edges per block in binning scatter
#define SLAB_CAP 5120   // per-bucket slab capacity (mean 4092, sd 64)
#define WPAD 136        // padded LDS row stride (halfs)

// ---- transpose + fp16-cast weights; blocks 0..3 also zero bfill
__global__ __launch_bounds__(128) void k_wprep(const float* __restrict__ W1,
                                               const float* __restrict__ W2,
                                               _Float16* __restrict__ WT1,
                                               _Float16* __restrict__ WT2,
                                               int* __restrict__ bfill) {
    int b = blockIdx.x;               // 0..255
    const float* W = (b < 128) ? W1 : W2;
    _Float16* WT = (b < 128) ? WT1 : WT2;
    int k = b & 127;
    int c = threadIdx.x;
    WT[c * 128 + k] = (_Float16)W[k * 128 + c];
    if (b < 4) bfill[b * 128 + c] = 0;   // 512 ints >= NBK
}

// ---- LDS-binned scatter of (src,dst) pairs into per-bucket slabs.
__global__ __launch_bounds__(256) void k_bscatter(const int* __restrict__ src,
                                                  const int* __restrict__ dst,
                                                  int* __restrict__ bfill,
                                                  int2* __restrict__ pairs,
                                                  int E, int nbk) {
    __shared__ int lcnt[1024];    // counts, then fill cursor (= lbase)
    __shared__ int delta[1024];   // slab_dest - lbase per bucket
    __shared__ int ssum[256];     // block-scan workspace
    __shared__ int2 stage[BSC_EDGES];
    int tid = threadIdx.x;
    int e0 = blockIdx.x * BSC_EDGES;
    int nloc = E - e0; if (nloc > BSC_EDGES) nloc = BSC_EDGES;

    for (int b = tid; b < nbk; b += 256) lcnt[b] = 0;
    __syncthreads();

    int d[BSC_EDGES / 256], s[BSC_EDGES / 256];
#pragma unroll
    for (int k = 0; k < BSC_EDGES / 256; ++k) {
        int e = e0 + k * 256 + tid;
        if (e < E) {
            d[k] = dst[e];
            s[k] = src[e];
            atomicAdd(&lcnt[d[k] >> BK_SHIFT], 1);
        } else d[k] = -1;
    }
    __syncthreads();

    const int gpb = (nbk + 255) >> 8;   // <=4 for nbk<=1024
    int c[4], mysum = 0;
    for (int t = 0; t < gpb; ++t) {
        int b = tid * gpb + t;
        c[t] = (b < nbk) ? lcnt[b] : 0;
        mysum += c[t];
    }
    ssum[tid] = mysum;
    __syncthreads();
    for (int off = 1; off < 256; off <<= 1) {
        int t = (tid >= off) ? ssum[tid - off] : 0;
        __syncthreads();
        ssum[tid] += t;
        __syncthreads();
    }
    int base = ssum[tid] - mysum;
    for (int t = 0; t < gpb; ++t) {
        int b = tid * gpb + t;
        if (b < nbk) {
            int g = c[t] ? atomicAdd(&bfill[b], c[t]) : 0;
            delta[b] = b * SLAB_CAP + g - base;   // slab dest - lbase
            lcnt[b] = base;                        // cursor starts at lbase
            base += c[t];
        }
    }
    __syncthreads();

#pragma unroll
    for (int k = 0; k < BSC_EDGES / 256; ++k) {
        if (d[k] >= 0) {
            int b = d[k] >> BK_SHIFT;
            int lp = atomicAdd(&lcnt[b], 1);
            int2 p; p.x = s[k]; p.y = d[k];
            stage[lp] = p;
        }
    }
    __syncthreads();

    for (int j = tid; j < nloc; j += 256) {
        int2 p = stage[j];
        pairs[delta[p.y >> BK_SHIFT] + j] = p;
    }
}

// ---- fused CSR build, one block per bucket slab (256 nodes)
__global__ __launch_bounds__(256) void k_csr(const int2* __restrict__ pairs,
                                             const int* __restrict__ bfill,
                                             int* __restrict__ row_start,
                                             int* __restrict__ cnt,
                                             float* __restrict__ dinv,
                                             int* __restrict__ srcs, int n) {
    __shared__ int lcnt[256];
    __shared__ int lpos[256];
    int tid = threadIdx.x;
    int b = blockIdx.x;
    lcnt[tid] = 0;
    __syncthreads();
    int beg = b * SLAB_CAP, end = beg + bfill[b];
    for (int i = beg + tid; i < end; i += 256)
        atomicAdd(&lcnt[pairs[i].y & 255], 1);
    __syncthreads();
    int c = lcnt[tid];
    lpos[tid] = c;
    __syncthreads();
    for (int off = 1; off < 256; off <<= 1) {
        int t = (tid >= off) ? lpos[tid - off] : 0;
        __syncthreads();
        lpos[tid] += t;
        __syncthreads();
    }
    int rs = beg + lpos[tid] - c;   // row start (slab-relative, gaps ok)
    int v = (b << BK_SHIFT) + tid;
    if (v < n) {
        row_start[v] = rs;
        cnt[v] = c;
        dinv[v] = rsqrtf((float)c + 1.0f);
    }
    __syncthreads();
    lpos[tid] = rs;                 // reuse as fill cursor
    __syncthreads();
    for (int i = beg + tid; i < end; i += 256) {
        int2 p = pairs[i];
        int loc = atomicAdd(&lpos[p.y & 255], 1);
        srcs[loc] = p.x;
    }
}

// ---------------------------------------------------------------------------
// MFMA GEMM: G[r][c] = dinv[r] * sum_k A[r][k]*W[k][c]   (N x 128)@(128 x 128)
// A fp32 (layer 1: x) or fp16 (layer 2: z1); WT = fp16 W^T staged in LDS.
// Block 256 thr = 4 waves, M=32/wave -> 128 rows/block (R10-proven shape).
// ---------------------------------------------------------------------------
template <typename AT>
__global__ __launch_bounds__(256) void k_gemm_mfma(const AT* __restrict__ X,
                                                   const _Float16* __restrict__ WT,
                                                   const float* __restrict__ dinv,
                                                   _Float16* __restrict__ G, int n) {
    __shared__ _Float16 Wl[128 * WPAD];
    int tid = threadIdx.x;
    {
        const half8* w8 = (const half8*)WT;
#pragma unroll
        for (int i = 0; i < 8; ++i) {
            int idx = i * 256 + tid;
            int r = idx >> 4, cc = idx & 15;
            *(half8*)(Wl + r * WPAD + cc * 8) = w8[idx];
        }
    }
    __syncthreads();

    auto loadA = [](const AT* p) -> half8 {
        if constexpr (sizeof(AT) == 4) {
            const float4* f = (const float4*)p;
            float4 f0 = f[0], f1 = f[1];
            half8 a;
            a[0] = (_Float16)f0.x; a[1] = (_Float16)f0.y;
            a[2] = (_Float16)f0.z; a[3] = (_Float16)f0.w;
            a[4] = (_Float16)f1.x; a[5] = (_Float16)f1.y;
            a[6] = (_Float16)f1.z; a[7] = (_Float16)f1.w;
            return a;
        } else {
            return *(const half8*)p;
        }
    };

    int wave = tid >> 6, lane = tid & 63;
    int q = lane >> 4, ln = lane & 15;
    int m0 = blockIdx.x * 128 + wave * 32;
    int mA0 = m0 + ln;      if (mA0 >= n) mA0 = n - 1;
    int mA1 = m0 + 16 + ln; if (mA1 >= n) mA1 = n - 1;
    const AT* xr0 = X + (size_t)mA0 * 128;
    const AT* xr1 = X + (size_t)mA1 * 128;

    floatx4 acc[2][8];
#pragma unroll
    for (int p = 0; p < 2; ++p)
#pragma unroll
        for (int t = 0; t < 8; ++t) acc[p][t] = (floatx4){0.f, 0.f, 0.f, 0.f};

#pragma unroll
    for (int kc = 0; kc < 128; kc += 32) {
        half8 a0 = loadA(xr0 + kc + q * 8);
        half8 a1 = loadA(xr1 + kc + q * 8);
#pragma unroll
        for (int t = 0; t < 8; ++t) {
            half8 b = *(const half8*)(Wl + (size_t)(t * 16 + ln) * WPAD + kc + q * 8);
            acc[0][t] = __builtin_amdgcn_mfma_f32_16x16x32_f16(a0, b, acc[0][t], 0, 0, 0);
            acc[1][t] = __builtin_amdgcn_mfma_f32_16x16x32_f16(a1, b, acc[1][t], 0, 0, 0);
        }
    }

#pragma unroll
    for (int p = 0; p < 2; ++p) {
#pragma unroll
        for (int r = 0; r < 4; ++r) {
            int row = m0 + p * 16 + q * 4 + r;
            if (row < n) {
                float dv = dinv[row];
                _Float16* grow = G + (size_t)row * 128 + ln;
#pragma unroll
                for (int t = 0; t < 8; ++t)
                    grow[t * 16] = (_Float16)(acc[p][t][r] * dv);
            }
        }
    }
}

// ---------------------------------------------------------------------------
// Gather + bias + relu -> Z (fp16). 16 lanes/node, half8 rows, fp32 accum.
// Proven 61 µs shape (R8): memory-bound at the random-row service rate.
// ---------------------------------------------------------------------------
__global__ __launch_bounds__(256) void k_gather_relu(const _Float16* __restrict__ G,
                                                     const int* __restrict__ srcs,
                                                     const int* __restrict__ row_start,
                                                     const int* __restrict__ cnt,
                                                     const float* __restrict__ dinv,
                                                     const float* __restrict__ bias,
                                                     _Float16* __restrict__ Z, int n) {
    int v = blockIdx.x * 16 + (threadIdx.x >> 4);
    int lane = threadIdx.x & 15;
    if (v >= n) return;
    const half8* G8 = (const half8*)G;

    half8 self = G8[(size_t)v * 16 + lane];
    float acc[8], acc2[8];
#pragma unroll
    for (int j = 0; j < 8; ++j) { acc[j] = (float)self[j]; acc2[j] = 0.f; }

    int beg = row_start[v], deg = cnt[v];
    int e = 0;
    for (; e + 3 < deg; e += 4) {
        int s0 = srcs[beg + e];
        int s1 = srcs[beg + e + 1];
        int s2 = srcs[beg + e + 2];
        int s3 = srcs[beg + e + 3];
        half8 t0 = G8[(size_t)s0 * 16 + lane];
        half8 t1 = G8[(size_t)s1 * 16 + lane];
        half8 t2 = G8[(size_t)s2 * 16 + lane];
        half8 t3 = G8[(size_t)s3 * 16 + lane];
#pragma unroll
        for (int j = 0; j < 8; ++j) {
            acc[j]  += (float)t0[j] + (float)t1[j];
            acc2[j] += (float)t2[j] + (float)t3[j];
        }
    }
    for (; e < deg; ++e) {
        int s0 = srcs[beg + e];
        half8 t0 = G8[(size_t)s0 * 16 + lane];
#pragma unroll
        for (int j = 0; j < 8; ++j) acc[j] += (float)t0[j];
    }

    float dv = dinv[v];
    const float4* b4 = (const float4*)bias;
    float4 bb0 = b4[lane * 2], bb1 = b4[lane * 2 + 1];
    float bf[8] = {bb0.x, bb0.y, bb0.z, bb0.w, bb1.x, bb1.y, bb1.z, bb1.w};
    half8 zo;
#pragma unroll
    for (int j = 0; j < 8; ++j) {
        float z = dv * (acc[j] + acc2[j]) + bf[j];
        zo[j] = (_Float16)fmaxf(z, 0.f);
    }
    ((half8*)Z)[(size_t)v * 16 + lane] = zo;
}

// ---------------------------------------------------------------------------
// Decode: out[e] = dot(Z[s_e], Z[d_e]) over 128 dims (fp16 rows, fp32 accum).
// ---------------------------------------------------------------------------
__global__ __launch_bounds__(256) void k_decode(const _Float16* __restrict__ Z,
                                                const int* __restrict__ eli,
                                                float* __restrict__ out, int el) {
    int sub = threadIdx.x >> 4, lane = threadIdx.x & 15;
    int e = blockIdx.x * 16 + sub;
    if (e >= el) return;
    int s = eli[e], d = eli[el + e];
    const half8* Z8 = (const half8*)Z;
    half8 a = Z8[(size_t)s * 16 + lane];
    half8 b = Z8[(size_t)d * 16 + lane];
    float dot = 0.f;
#pragma unroll
    for (int j = 0; j < 8; ++j) dot += (float)a[j] * (float)b[j];
#pragma unroll
    for (int off = 8; off; off >>= 1) dot += __shfl_down(dot, off, 16);
    if (lane == 0) out[e] = dot;
}

extern "C" void kernel_launch(void* const* d_in, const int* in_sizes, int n_in,
                              void* d_out, int out_size, void* d_ws, size_t ws_size,
                              hipStream_t stream) {
    const float* x  = (const float*)d_in[0];
    const int*  ei  = (const int*)d_in[1];
    const int*  eli = (const int*)d_in[2];
    const float* W1 = (const float*)d_in[3];
    const float* b1 = (const float*)d_in[4];
    const float* W2 = (const float*)d_in[5];
    const float* b2 = (const float*)d_in[6];
    float* out = (float*)d_out;

    const int N  = in_sizes[0] / 128;
    const int E  = in_sizes[1] / 2;
    const int EL = in_sizes[2] / 2;
    const int* src = ei;
    const int* dst = ei + E;
    const int NBK = (N + 255) >> BK_SHIFT;   // 391 for N=100000

    char* ws = (char*)d_ws;
    size_t off = 0;
    auto alloc = [&](size_t bytes) -> void* {
        void* p = ws + off;
        off += bytes;
        off = (off + 255) & ~(size_t)255;
        return p;
    };
    int*       cnt       = (int*)alloc((size_t)N * 4);
    int*       row_start = (int*)alloc((size_t)N * 4);
    float*     dinv      = (float*)alloc((size_t)N * 4);
    int*       bfill     = (int*)alloc(4096);
    _Float16*  WT1       = (_Float16*)alloc(128 * 128 * 2);
    _Float16*  WT2       = (_Float16*)alloc(128 * 128 * 2);
    int*       srcs      = (int*)alloc((size_t)NBK * SLAB_CAP * 4);
    int2*      pairs     = (int2*)alloc((size_t)NBK * SLAB_CAP * 8);
    _Float16*  buf0      = (_Float16*)alloc((size_t)N * 128 * 2);  // G1 -> G2
    _Float16*  buf1      = (_Float16*)alloc((size_t)N * 128 * 2);  // z1 -> z2

    // weight prep + bfill zero (one launch)
    k_wprep<<<256, 128, 0, stream>>>(W1, W2, WT1, WT2, bfill);

    // CSR build: slab bucket sort (no count/scan pre-pass)
    k_bscatter<<<(E + BSC_EDGES - 1) / BSC_EDGES, 256, 0, stream>>>(src, dst, bfill, pairs, E, NBK);
    k_csr<<<NBK, 256, 0, stream>>>(pairs, bfill, row_start, cnt, dinv, srcs, N);

    // layer 1: g1 = (x@W1)*dinv -> buf0 ; z1 = relu(agg(g1)+b1) -> buf1
    k_gemm_mfma<float><<<(N + 127) / 128, 256, 0, stream>>>(x, WT1, dinv, buf0, N);
    k_gather_relu<<<(N + 15) / 16, 256, 0, stream>>>(buf0, srcs, row_start, cnt, dinv, b1, buf1, N);
    // layer 2: g2 = (z1@W2)*dinv -> buf0 ; z2 = relu(agg(g2)+b2) -> buf1
    k_gemm_mfma<_Float16><<<(N + 127) / 128, 256, 0, stream>>>(buf1, WT2, dinv, buf0, N);
    k_gather_relu<<<(N + 15) / 16, 256, 0, stream>>>(buf0, srcs, row_start, cnt, dinv, b2, buf1, N);
    // decode
    k_decode<<<(EL + 15) / 16, 256, 0, stream>>>(buf1, eli, out, EL);
}